// Round 22
// baseline (148.280 us; speedup 1.0000x reference)
//
#include <hip/hip_runtime.h>
#include <hip/hip_bf16.h>
#include <math.h>

#define D_MODEL 512
#define HEADS   8
#define D_K     64
#define T_SEQ   2048
#define B_SZ    4
#define NROWS   (B_SZ * T_SEQ)   // 8192
#define KVB     64
#define KSPLIT  2
#define KHALF   (T_SEQ / KSPLIT) // 1024

#define BKG 64

typedef __attribute__((ext_vector_type(8))) short short8;
typedef __attribute__((ext_vector_type(4))) float f32x4;
typedef __attribute__((ext_vector_type(4))) ushort bf16x4;
typedef __attribute__((ext_vector_type(4))) unsigned int u32x4;

typedef __attribute__((address_space(1))) const unsigned int as1_uint;
typedef __attribute__((address_space(3))) unsigned int as3_uint;

__device__ __forceinline__ ushort f2bf(float f) {
    union { float f; unsigned u; } v; v.f = f;
    unsigned u = v.u;
    unsigned r = (u + 0x7FFFu + ((u >> 16) & 1u)) >> 16;
    return (ushort)r;
}
__device__ __forceinline__ float bf2f(ushort u) {
    union { unsigned u; float f; } v; v.u = ((unsigned)u) << 16;
    return v.f;
}
__device__ __forceinline__ unsigned pk_bf16(float lo, float hi) {
    unsigned r;
    asm("v_cvt_pk_bf16_f32 %0, %1, %2" : "=v"(r) : "v"(lo), "v"(hi));
    return r;
}

// ---------------------------------------------------------------- fused prep
__global__ __launch_bounds__(256) void k_prep(
    const int* __restrict__ tokens, const float* __restrict__ emb,
    const float* __restrict__ wq, const float* __restrict__ wk,
    const float* __restrict__ wv, const float* __restrict__ wo,
    const float* __restrict__ w1, const float* __restrict__ w2,
    const float* __restrict__ bq, const float* __restrict__ bk,
    const float* __restrict__ bv,
    ushort* __restrict__ xb, float* __restrict__ mask_out,
    ushort* __restrict__ wqkvT, ushort* __restrict__ woT,
    ushort* __restrict__ w1T, ushort* __restrict__ w2T,
    float* __restrict__ bqkv, float qsc)
{
    __shared__ ushort tls[32][33];
    int bid = blockIdx.x, tid = threadIdx.x;
    if (bid < 4096) {
        int row = bid * 2 + (tid >> 7);
        int t   = row & (T_SEQ - 1);
        int tok = tokens[row];
        int t2  = tid & 127;
        if (t2 == 0) mask_out[row] = (tok == 0) ? 1.0f : 0.0f;
        const float* e = emb + (size_t)tok * D_MODEL;
#pragma unroll
        for (int i = 0; i < 4; ++i) {
            int d = t2 + 128 * i;
            float freq = exp2f(-(float)(d & ~1) * 0.025952563240330564f);
            float sn, cs;
            __sincosf((float)t * freq, &sn, &cs);
            float x = e[d] * 22.627416997969522f + ((d & 1) ? cs : sn);
            xb[(size_t)row * D_MODEL + d] = f2bf(x);
        }
        return;
    }
    const float* src; ushort* dst; float scale = 1.0f; int K, N, bx, by;
    if (bid < 5120) {
        int b = bid - 4096; int z = b >> 8; int rem = b & 255;
        bx = rem & 15; by = rem >> 4; K = 512; N = 512;
        src = (z == 0) ? wq : (z == 1) ? wk : (z == 2) ? wv : wo;
        dst = (z < 3) ? wqkvT + (size_t)z * 512 * 512 : woT;
        scale = (z == 0) ? qsc : 1.0f;
    } else if (bid < 5632) {
        int b = bid - 5120; bx = b & 31; by = b >> 5; K = 512; N = 1024; src = w1; dst = w1T;
    } else if (bid < 6144) {
        int b = bid - 5632; bx = b & 15; by = b >> 4; K = 1024; N = 512; src = w2; dst = w2T;
    } else {
        int i = (bid - 6144) * 256 + tid;
        if (i < 512)       bqkv[i] = bq[i] * qsc;
        else if (i < 1024) bqkv[i] = bk[i - 512];
        else if (i < 1536) bqkv[i] = bv[i - 1024];
        return;
    }
    int tx = tid & 31, ty = tid >> 5;
    int n0 = bx * 32, k0 = by * 32;
#pragma unroll
    for (int i = 0; i < 4; ++i)
        tls[ty + i * 8][tx] = f2bf(src[(size_t)(k0 + ty + i * 8) * N + n0 + tx] * scale);
    __syncthreads();
#pragma unroll
    for (int i = 0; i < 4; ++i)
        dst[(size_t)(n0 + ty + i * 8) * K + k0 + tx] = tls[tx][ty + i * 8];
}

// ---------------------------------------------------------------- LDS-staged GEMM
// BMT x BNT tile, 4 waves (2x2), BK=64, dbuf.
// COMBA: A reg-staged as (O0+O1)/(l0+l1) (fused KSPLIT combine + normalize).
// MODE 0: bf16 out (+ReLU opt); 1: f32 out;
// MODE 2: QKV split; V written COLUMN-PERMUTED (tau^-1) so attn can DMA it.
template<int MODE, bool RELU, int BMT, int BNT, bool COMBA>
__global__ __launch_bounds__(256) void k_gemm_lds(
    const ushort* __restrict__ A, const ushort* __restrict__ A2,
    const float* __restrict__ lpb,
    const ushort* __restrict__ BT,
    const float* __restrict__ bias, void* __restrict__ C0,
    void* __restrict__ C1, void* __restrict__ C2,
    int M, int N, int K)
{
    constexpr int MR = BMT / 32;
    constexpr int NR = BNT / 32;
    __shared__ __attribute__((aligned(16))) ushort As[2][BMT * BKG];
    __shared__ __attribute__((aligned(16))) ushort Bs[2][BNT * BKG];

    const int tid = threadIdx.x;
    const int w = tid >> 6, l = tid & 63;
    const int lr = l & 15, lg = l >> 4;
    const int wr = w >> 1, wc = w & 1;

    int bx = blockIdx.x, by = blockIdx.y;
    {   // XCD-aware swizzle (bijective; gridDim.y % 8 == 0 for all our calls)
        int nx = gridDim.x, ny = gridDim.y;
        if ((ny & 7) == 0) {
            int lin = bx + nx * by;
            int xcd = lin & 7, idx = lin >> 3;
            int per = ny >> 3;
            by = xcd * per + (idx % per);
            bx = idx / per;
        }
    }
    const int brow0 = by * BMT;
    const int bcol0 = bx * BNT;
    const int swz = lr & 7;

    f32x4 acc[MR][NR] = {};
    const int nks = K >> 6;

#define STAGE_B(buf, k0)                                                        \
    {                                                                           \
        _Pragma("unroll")                                                       \
        for (int i = 0; i < BNT / 32; ++i) {                                    \
            int gi = w * (BNT * 2) + i * 64 + l;                                \
            int row = gi >> 3, slot = gi & 7;                                   \
            int g = slot ^ (row & 7);                                           \
            __builtin_amdgcn_global_load_lds(                                   \
                (as1_uint*)(BT + (size_t)(bcol0 + row) * K + (k0) + g * 8),     \
                (as3_uint*)(&Bs[buf][gi * 8]), 16, 0, 0);                       \
        }                                                                       \
    }
#define STAGE_A_DMA(buf, k0)                                                    \
    {                                                                           \
        _Pragma("unroll")                                                       \
        for (int i = 0; i < BMT / 32; ++i) {                                    \
            int gi = w * (BMT * 2) + i * 64 + l;                                \
            int row = gi >> 3, slot = gi & 7;                                   \
            int g = slot ^ (row & 7);                                           \
            __builtin_amdgcn_global_load_lds(                                   \
                (as1_uint*)(A + (size_t)(brow0 + row) * K + (k0) + g * 8),      \
                (as3_uint*)(&As[buf][gi * 8]), 16, 0, 0);                       \
        }                                                                       \
    }
#define STAGE_A_COMB(buf, k0)                                                   \
    {                                                                           \
        int head = (k0) >> 6;                                                   \
        _Pragma("unroll")                                                       \
        for (int i = 0; i < BMT / 32; ++i) {                                    \
            int gi = w * (BMT * 2) + i * 64 + l;                                \
            int row = gi >> 3, slot = gi & 7;                                   \
            int g = slot ^ (row & 7);                                           \
            size_t off = (size_t)(brow0 + row) * K + (k0) + g * 8;              \
            bf16x4 a0 = *(const bf16x4*)(A + off);                              \
            bf16x4 a1 = *(const bf16x4*)(A + off + 4);                          \
            bf16x4 c0 = *(const bf16x4*)(A2 + off);                             \
            bf16x4 c1 = *(const bf16x4*)(A2 + off + 4);                         \
            float l0 = lpb[(size_t)head * NROWS + brow0 + row];                 \
            float l1 = lpb[(size_t)(8 + head) * NROWS + brow0 + row];           \
            float r = 1.0f / (l0 + l1);                                         \
            u32x4 pk;                                                           \
            pk[0] = pk_bf16((bf2f(a0[0]) + bf2f(c0[0])) * r,                    \
                            (bf2f(a0[1]) + bf2f(c0[1])) * r);                   \
            pk[1] = pk_bf16((bf2f(a0[2]) + bf2f(c0[2])) * r,                    \
                            (bf2f(a0[3]) + bf2f(c0[3])) * r);                   \
            pk[2] = pk_bf16((bf2f(a1[0]) + bf2f(c1[0])) * r,                    \
                            (bf2f(a1[1]) + bf2f(c1[1])) * r);                   \
            pk[3] = pk_bf16((bf2f(a1[2]) + bf2f(c1[2])) * r,                    \
                            (bf2f(a1[3]) + bf2f(c1[3])) * r);                   \
            *(u32x4*)(&As[buf][gi * 8]) = pk;                                   \
        }                                                                       \
    }
#define STAGE(buf, k0)                                                          \
    {                                                                           \
        if constexpr (COMBA) { STAGE_A_COMB(buf, k0); }                         \
        else                 { STAGE_A_DMA(buf, k0); }                          \
        STAGE_B(buf, k0);                                                       \
    }

    STAGE(0, 0);
    __syncthreads();

    int buf = 0;
    for (int ks = 0; ks < nks; ++ks) {
        if (ks + 1 < nks) STAGE(buf ^ 1, (ks + 1) * BKG);
#pragma unroll
        for (int kk = 0; kk < 2; ++kk) {
            short8 af[MR], bfr[NR];
#pragma unroll
            for (int m = 0; m < MR; ++m) {
                int row = wr * (BMT / 2) + m * 16 + lr;
                int slot = (kk * 4 + lg) ^ swz;
                af[m] = *(const short8*)(&As[buf][row * 64 + slot * 8]);
            }
#pragma unroll
            for (int n = 0; n < NR; ++n) {
                int row = wc * (BNT / 2) + n * 16 + lr;
                int slot = (kk * 4 + lg) ^ swz;
                bfr[n] = *(const short8*)(&Bs[buf][row * 64 + slot * 8]);
            }
#pragma unroll
            for (int m = 0; m < MR; ++m)
#pragma unroll
                for (int n = 0; n < NR; ++n)
                    acc[m][n] = __builtin_amdgcn_mfma_f32_16x16x32_bf16(af[m], bfr[n], acc[m][n], 0, 0, 0);
        }
        __syncthreads();
        buf ^= 1;
    }
#undef STAGE
#undef STAGE_A_COMB
#undef STAGE_A_DMA
#undef STAGE_B

#pragma unroll
    for (int n = 0; n < NR; ++n) {
        int col = bcol0 + wc * (BNT / 2) + n * 16 + lr;
        float bv = bias[col];
#pragma unroll
        for (int m = 0; m < MR; ++m) {
            int row0 = brow0 + wr * (BMT / 2) + m * 16 + 4 * lg;
            if constexpr (MODE == 2) {
                int seg = col >> 9, lc = col & 511;
                if (seg == 2) {
                    bf16x4 pk;
#pragma unroll
                    for (int j = 0; j < 4; ++j) pk[j] = f2bf(acc[m][n][j] + bv);
                    // tau^-1 column permutation: key 4-group kg -> position
                    // 32*k3 + 16*k1 + 8*k0 + 4*k2 within its 64-key tile.
                    int kg  = (row0 >> 2) & 15;
                    int pos = (row0 & ~63) + ((kg & 8) << 2) + ((kg & 2) << 3)
                              + ((kg & 1) << 3) + (kg & 4);
                    *(bf16x4*)((ushort*)C2 + (size_t)lc * M + pos) = pk;
                } else {
                    ushort* dst = (seg == 0) ? (ushort*)C0 : (ushort*)C1;
#pragma unroll
                    for (int j = 0; j < 4; ++j)
                        dst[(size_t)(row0 + j) * 512 + lc] = f2bf(acc[m][n][j] + bv);
                }
            } else if constexpr (MODE == 0) {
#pragma unroll
                for (int j = 0; j < 4; ++j) {
                    float v = acc[m][n][j] + bv;
                    if (RELU) v = fmaxf(v, 0.0f);
                    ((ushort*)C0)[(size_t)(row0 + j) * N + col] = f2bf(v);
                }
            } else {
#pragma unroll
                for (int j = 0; j < 4; ++j)
                    ((float*)C0)[(size_t)(row0 + j) * N + col] = acc[m][n][j] + bv;
            }
        }
    }
}

// ---------------------------------------------------------------- flash attention
// 8 waves x 32 q-rows (2 q-subtiles share K/V register fragments). KSPLIT=2.
// K AND V both staged via global_load_lds (V pre-permuted in QKV epilogue).
// Static-max exp2 softmax; l via ones-MFMA.
__global__ __launch_bounds__(512, 4) void k_attn(
    const ushort* __restrict__ Q, const ushort* __restrict__ Kb,
    const ushort* __restrict__ Vt, const int* __restrict__ tokens,
    ushort* __restrict__ O0, ushort* __restrict__ O1,
    float* __restrict__ lp)
{
    __shared__ __attribute__((aligned(16))) ushort Kl[2][KVB * 64];
    __shared__ __attribute__((aligned(16))) ushort Vl[2][KVB * 64];
    __shared__ __attribute__((aligned(16))) ushort Mbh[KHALF];
    __shared__ int padf[KHALF / KVB];

    const int tid = threadIdx.x;
    const int w = tid >> 6, l = tid & 63;
    const int lr = l & 15, lg = l >> 4;
    const int swz = lr & 7;

    // XCD swizzle: lin bijective over 0..511 (grid 8x8x8)
    int lin = blockIdx.x + 8 * (blockIdx.y + 8 * blockIdx.z);  // 0..511
    int xcd = lin & 7, idx = lin >> 3;           // idx 0..63
    int qt  = idx & 7;
    int grp = xcd + 8 * (idx >> 3);              // 0..63
    int ks  = grp & 1;
    int h   = (grp >> 1) & 7;
    int b   = grp >> 4;

    const int q0  = qt * 256 + w * 32;
    const int kb0 = ks * KHALF;

    // staging geometry: thread -> row srow (0..63), granule sg (0..7),
    // pre-swizzled source granule sgx; both K and V DMA'd linearly.
    const int gi   = w * 64 + l;
    const int srow = gi >> 3;
    const int sg   = gi & 7;
    const int sgx  = sg ^ (srow & 7);
    const ushort* Ksrc = Kb + ((size_t)(b * T_SEQ + kb0) + srow) * D_MODEL + h * D_K + sgx * 8;
    const ushort* Vsrc = Vt + (size_t)(h * D_K + srow) * NROWS + b * T_SEQ + kb0 + sgx * 8;

#define KVSTAGE(bufi, kt_)                                                      \
    {                                                                           \
        __builtin_amdgcn_global_load_lds(                                       \
            (as1_uint*)(Ksrc + (size_t)(kt_) * KVB * D_MODEL),                  \
            (as3_uint*)(&Kl[bufi][gi * 8]), 16, 0, 0);                          \
        __builtin_amdgcn_global_load_lds(                                       \
            (as1_uint*)(Vsrc + (kt_) * KVB),                                    \
            (as3_uint*)(&Vl[bufi][gi * 8]), 16, 0, 0);                          \
    }

    const ushort* Qh = Q + (size_t)b * T_SEQ * D_MODEL + h * D_K;
    short8 aq[2][2];
#pragma unroll
    for (int qs = 0; qs < 2; ++qs)
#pragma unroll
        for (int c2 = 0; c2 < 2; ++c2)
            aq[qs][c2] = *(const short8*)(Qh + (size_t)(q0 + qs * 16 + lr) * D_MODEL
                                          + c2 * 32 + 8 * lg);

    // ones vector (bf16 1.0) for l-sum MFMA
    short8 vones;
#pragma unroll
    for (int i = 0; i < 8; ++i) vones[i] = (short)0x3F80;

    // mask staging (bf16) + per-tile pad bitmap for this key half
    const int* tk = tokens + b * T_SEQ + kb0;
#pragma unroll
    for (int it = 0; it < KHALF / 512; ++it) {
        int i = tid + it * 512;
        bool pad = (tk[i] == 0);
        Mbh[i] = pad ? (ushort)0xFF7F : (ushort)0;
        unsigned long long bal = __ballot(pad);
        if (l == 0) padf[it * 8 + w] = (bal != 0ull);
    }

    f32x4 acc[2][4] = {};
    f32x4 acc_l[2] = {};

    KVSTAGE(0, 0);
    __syncthreads();

    int buf = 0;
    const int NT = KHALF / KVB;   // 16
#pragma unroll 2
    for (int kt = 0; kt < NT; ++kt) {
        if (kt + 1 < NT) KVSTAGE(buf ^ 1, kt + 1);

        const ushort* Kt = Kl[buf];
        const ushort* Vb = Vl[buf];
        bool havePad = padf[kt];

        // ---- QK^T + softmax, kb-pairs; K-frags shared by both q-subtiles
        unsigned dw[2][4][2];   // [qs][kb][half] packed bf16 P pairs
#pragma unroll
        for (int kh = 0; kh < 2; ++kh) {
            short8 kf[2][2];
#pragma unroll
            for (int i = 0; i < 2; ++i)
#pragma unroll
                for (int c2 = 0; c2 < 2; ++c2)
                    kf[i][c2] = *(const short8*)((const char*)Kt
                                + ((2 * kh + i) * 16 + lr) * 128
                                + (((c2 * 4 + lg) ^ swz) * 16));
#pragma unroll
            for (int qs = 0; qs < 2; ++qs)
#pragma unroll
                for (int i = 0; i < 2; ++i) {
                    int kb = 2 * kh + i;
                    __builtin_amdgcn_s_setprio(1);
                    f32x4 sf = {};
                    sf = __builtin_amdgcn_mfma_f32_16x16x32_bf16(kf[i][0], aq[qs][0], sf, 0, 0, 0);
                    sf = __builtin_amdgcn_mfma_f32_16x16x32_bf16(kf[i][1], aq[qs][1], sf, 0, 0, 0);
                    __builtin_amdgcn_s_setprio(0);
                    if (havePad) {
                        bf16x4 m4 = *(const bf16x4*)(Mbh + kt * KVB + kb * 16 + 4 * lg);
#pragma unroll
                        for (int j = 0; j < 4; ++j) sf[j] += bf2f(m4[j]);
                    }
                    dw[qs][kb][0] = pk_bf16(exp2f(sf[0]), exp2f(sf[1]));
                    dw[qs][kb][1] = pk_bf16(exp2f(sf[2]), exp2f(sf[3]));
                }
        }

        // ---- PV, c-pairs; V-frags shared by both q-subtiles; l via ones-MFMA
#pragma unroll
        for (int ch = 0; ch < 2; ++ch) {
            short8 vf[2][2];
#pragma unroll
            for (int i = 0; i < 2; ++i)
#pragma unroll
                for (int kk = 0; kk < 2; ++kk)
                    vf[i][kk] = *(const short8*)((const char*)Vb
                                + ((2 * ch + i) * 16 + lr) * 128
                                + (((kk * 4 + lg) ^ swz) * 16));
            __builtin_amdgcn_s_setprio(1);
#pragma unroll
            for (int qs = 0; qs < 2; ++qs) {
                u32x4 pw0 = { dw[qs][0][0], dw[qs][0][1], dw[qs][1][0], dw[qs][1][1] };
                u32x4 pw1 = { dw[qs][2][0], dw[qs][2][1], dw[qs][3][0], dw[qs][3][1] };
                short8 pa0 = __builtin_bit_cast(short8, pw0);
                short8 pa1 = __builtin_bit_cast(short8, pw1);
#pragma unroll
                for (int i = 0; i < 2; ++i) {
                    int c = 2 * ch + i;
                    acc[qs][c] = __builtin_amdgcn_mfma_f32_16x16x32_bf16(vf[i][0], pa0, acc[qs][c], 0, 0, 0);
                    acc[qs][c] = __builtin_amdgcn_mfma_f32_16x16x32_bf16(vf[i][1], pa1, acc[qs][c], 0, 0, 0);
                }
                if (ch == 0) {
                    acc_l[qs] = __builtin_amdgcn_mfma_f32_16x16x32_bf16(vones, pa0, acc_l[qs], 0, 0, 0);
                    acc_l[qs] = __builtin_amdgcn_mfma_f32_16x16x32_bf16(vones, pa1, acc_l[qs], 0, 0, 0);
                }
            }
            __builtin_amdgcn_s_setprio(0);
        }

        __syncthreads();
        buf ^= 1;
    }
#undef KVSTAGE

    // ---- unnormalized partial output + l (all rows of acc_l equal l[q=lr])
    ushort* Op = (ks == 0) ? O0 : O1;
#pragma unroll
    for (int qs = 0; qs < 2; ++qs) {
        ushort* orow = Op + (size_t)(b * T_SEQ + q0 + qs * 16 + lr) * D_MODEL + h * D_K;
#pragma unroll
        for (int c = 0; c < 4; ++c) {
            bf16x4 pk;
#pragma unroll
            for (int j = 0; j < 4; ++j) pk[j] = f2bf(acc[qs][c][j]);
            *(bf16x4*)(orow + c * 16 + 4 * lg) = pk;
        }
        if (l < 16)
            lp[(size_t)(ks * 8 + h) * NROWS + b * T_SEQ + q0 + qs * 16 + l] = acc_l[qs][0];
    }
}

// ---------------------------------------------------------------- add + layernorm
template<bool A_BF16, bool RES_BF16, bool OUT_F32>
__global__ __launch_bounds__(256) void k_ln(
    const void* __restrict__ A, const void* __restrict__ Res,
    const float* __restrict__ g, const float* __restrict__ bb,
    float* __restrict__ of, ushort* __restrict__ ob)
{
    int row = blockIdx.x * 4 + (threadIdx.x >> 6);
    int l = threadIdx.x & 63;
    float v[8];
    float s = 0.0f, ss = 0.0f;
#pragma unroll
    for (int i = 0; i < 2; ++i) {
        int d0 = i * 256 + l * 4;
        f32x4 va, vb;
        if (A_BF16) {
            bf16x4 t = *(const bf16x4*)((const ushort*)A + (size_t)row * D_MODEL + d0);
#pragma unroll
            for (int j = 0; j < 4; ++j) va[j] = bf2f(t[j]);
        } else {
            va = *(const f32x4*)((const float*)A + (size_t)row * D_MODEL + d0);
        }
        if (RES_BF16) {
            bf16x4 t = *(const bf16x4*)((const ushort*)Res + (size_t)row * D_MODEL + d0);
#pragma unroll
            for (int j = 0; j < 4; ++j) vb[j] = bf2f(t[j]);
        } else {
            vb = *(const f32x4*)((const float*)Res + (size_t)row * D_MODEL + d0);
        }
#pragma unroll
        for (int j = 0; j < 4; ++j) {
            float x = va[j] + vb[j];
            v[i * 4 + j] = x; s += x; ss += x * x;
        }
    }
#pragma unroll
    for (int d = 1; d < 64; d <<= 1) { s += __shfl_xor(s, d); ss += __shfl_xor(ss, d); }
    float mu  = s * (1.0f / 512.0f);
    float var = ss * (1.0f / 512.0f) - mu * mu;
    float rs  = rsqrtf(var + 1e-5f);
#pragma unroll
    for (int i = 0; i < 2; ++i)
#pragma unroll
        for (int j = 0; j < 4; ++j) {
            int d = i * 256 + l * 4 + j;
            float o = (v[i * 4 + j] - mu) * rs * g[d] + bb[d];
            if (OUT_F32) of[(size_t)row * D_MODEL + d] = o;
            else         ob[(size_t)row * D_MODEL + d] = f2bf(o);
        }
}

// ---------------------------------------------------------------- launcher
extern "C" void kernel_launch(void* const* d_in, const int* in_sizes, int n_in,
                              void* d_out, int out_size, void* d_ws, size_t ws_size,
                              hipStream_t stream)
{
    const int*   tokens = (const int*)  d_in[0];
    const float* emb    = (const float*)d_in[1];
    const float* wq     = (const float*)d_in[2];
    const float* bq     = (const float*)d_in[3];
    const float* wk     = (const float*)d_in[4];
    const float* bk     = (const float*)d_in[5];
    const float* wv     = (const float*)d_in[6];
    const float* bv     = (const float*)d_in[7];
    const float* wo     = (const float*)d_in[8];
    const float* bo     = (const float*)d_in[9];
    const float* w1     = (const float*)d_in[10];
    const float* b1     = (const float*)d_in[11];
    const float* w2     = (const float*)d_in[12];
    const float* b2     = (const float*)d_in[13];
    const float* ln1_g  = (const float*)d_in[14];
    const float* ln1_b  = (const float*)d_in[15];
    const float* ln2_g  = (const float*)d_in[16];
    const float* ln2_b  = (const float*)d_in[17];

    char* ws = (char*)d_ws;
    ushort* xb   = (ushort*)(ws + 0);              //  8 MB  x bf16 (LN1 residual)
    ushort* Qb   = (ushort*)(ws + 8388608);        //  8 MB  Q; then WO out
    ushort* Kbuf = (ushort*)(ws + 16777216);       //  8 MB  K \ later ff1 (16 MB)
    ushort* Vt   = (ushort*)(ws + 25165824);       //  8 MB  V^T permuted /
    ushort* atb  = (ushort*)(ws + 33554432);       //  8 MB  O-partial0; then h bf16
    ushort* AVb  = (ushort*)(ws + 41943040);       //  8 MB  O-partial1; then ff2
    ushort* wqkvT = (ushort*)(ws + 50331648);      // 1.5 MB
    ushort* woT  = wqkvT + 1536 * 512;
    ushort* w1T  = woT + 262144;
    ushort* w2T  = w1T + 524288;
    float*  bqkv = (float*)(w2T + 524288);         // 6 KB
    float*  lpart = bqkv + 2048;                   // 512 KB (2*8*NROWS f32)

    ushort* ff1b = Kbuf;
    ushort* ff2b = AVb;

    float* out_f    = (float*)d_out;
    float* mask_out = out_f + (size_t)NROWS * D_MODEL;

    // exp2-domain score scale: 1/sqrt(64) * log2(e)
    const float QSC = 0.18033688011112042f;

    k_prep<<<6150, 256, 0, stream>>>(
        tokens, emb, wq, wk, wv, wo, w1, w2, bq, bk, bv,
        xb, mask_out, wqkvT, woT, w1T, w2T, bqkv, QSC);

    // QKV: 128x64 tiles -> 1536 blocks, 3 blocks/CU (V written column-permuted)
    k_gemm_lds<2, false, 128, 64, false><<<dim3(24, 64), 256, 0, stream>>>(
        xb, nullptr, nullptr, wqkvT, bqkv, Qb, Kbuf, Vt, NROWS, 1536, 512);

    k_attn<<<dim3(8, 8, 8), 512, 0, stream>>>(
        Qb, Kbuf, Vt, tokens, atb, AVb, lpart);

    // WO GEMM with fused KSPLIT combine+normalize; 128x64 tiles; out -> Qb.
    k_gemm_lds<0, false, 128, 64, true><<<dim3(8, 64), 256, 0, stream>>>(
        atb, AVb, lpart, woT, bo, Qb, nullptr, nullptr, NROWS, 512, 512);

    // LN1: h = LN(wo_out + x) -> bf16 into atb
    k_ln<true, true, false><<<NROWS / 4, 256, 0, stream>>>(
        Qb, xb, ln1_g, ln1_b, nullptr, atb);

    // FF1: 128x64 tiles -> 1024 blocks
    k_gemm_lds<0, true, 128, 64, false><<<dim3(16, 64), 256, 0, stream>>>(
        atb, nullptr, nullptr, w1T, b1, ff1b, nullptr, nullptr, NROWS, 1024, 512);
    // FF2: 128x64 tiles -> 512 blocks
    k_gemm_lds<0, false, 128, 64, false><<<dim3(8, 64), 256, 0, stream>>>(
        ff1b, nullptr, nullptr, w2T, b2, ff2b, nullptr, nullptr, NROWS, 512, 1024);

    // LN2: out = LN(ff + h) -> f32 to d_out   (h = atb)
    k_ln<true, true, true><<<NROWS / 4, 256, 0, stream>>>(
        ff2b, atb, ln2_g, ln2_b, out_f, nullptr);
}

// Round 23
// 143.842 us; speedup vs baseline: 1.0309x; 1.0309x over previous
//
#include <hip/hip_runtime.h>
#include <hip/hip_bf16.h>
#include <math.h>

#define D_MODEL 512
#define HEADS   8
#define D_K     64
#define T_SEQ   2048
#define B_SZ    4
#define NROWS   (B_SZ * T_SEQ)   // 8192
#define KVB     64
#define KSPLIT  2
#define KHALF   (T_SEQ / KSPLIT) // 1024

#define BKG 64

typedef __attribute__((ext_vector_type(8))) short short8;
typedef __attribute__((ext_vector_type(4))) float f32x4;
typedef __attribute__((ext_vector_type(4))) ushort bf16x4;
typedef __attribute__((ext_vector_type(4))) unsigned int u32x4;

typedef __attribute__((address_space(1))) const unsigned int as1_uint;
typedef __attribute__((address_space(3))) unsigned int as3_uint;

__device__ __forceinline__ ushort f2bf(float f) {
    union { float f; unsigned u; } v; v.f = f;
    unsigned u = v.u;
    unsigned r = (u + 0x7FFFu + ((u >> 16) & 1u)) >> 16;
    return (ushort)r;
}
__device__ __forceinline__ float bf2f(ushort u) {
    union { unsigned u; float f; } v; v.u = ((unsigned)u) << 16;
    return v.f;
}
__device__ __forceinline__ unsigned pk_bf16(float lo, float hi) {
    unsigned r;
    asm("v_cvt_pk_bf16_f32 %0, %1, %2" : "=v"(r) : "v"(lo), "v"(hi));
    return r;
}

// ---------------------------------------------------------------- fused prep
// embed path vectorized: float4 loads, 2 sincos per 4 elems (pairs share angle)
__global__ __launch_bounds__(256) void k_prep(
    const int* __restrict__ tokens, const float* __restrict__ emb,
    const float* __restrict__ wq, const float* __restrict__ wk,
    const float* __restrict__ wv, const float* __restrict__ wo,
    const float* __restrict__ w1, const float* __restrict__ w2,
    const float* __restrict__ bq, const float* __restrict__ bk,
    const float* __restrict__ bv,
    ushort* __restrict__ xb, float* __restrict__ mask_out,
    ushort* __restrict__ wqkvT, ushort* __restrict__ woT,
    ushort* __restrict__ w1T, ushort* __restrict__ w2T,
    float* __restrict__ bqkv, float qsc)
{
    __shared__ ushort tls[32][33];
    int bid = blockIdx.x, tid = threadIdx.x;
    if (bid < 4096) {
        int row = bid * 2 + (tid >> 7);
        int t   = row & (T_SEQ - 1);
        int tok = tokens[row];
        int t2  = tid & 127;
        if (t2 == 0) mask_out[row] = (tok == 0) ? 1.0f : 0.0f;
        const float* e = emb + (size_t)tok * D_MODEL;
        int d0 = t2 * 4;
        f32x4 ev = *(const f32x4*)(e + d0);
        float fr0 = exp2f(-(float)d0 * 0.025952563240330564f);
        float fr1 = exp2f(-(float)(d0 + 2) * 0.025952563240330564f);
        float sn0, cs0, sn1, cs1;
        __sincosf((float)t * fr0, &sn0, &cs0);
        __sincosf((float)t * fr1, &sn1, &cs1);
        bf16x4 o;
        o[0] = f2bf(ev[0] * 22.627416997969522f + sn0);
        o[1] = f2bf(ev[1] * 22.627416997969522f + cs0);
        o[2] = f2bf(ev[2] * 22.627416997969522f + sn1);
        o[3] = f2bf(ev[3] * 22.627416997969522f + cs1);
        *(bf16x4*)(xb + (size_t)row * D_MODEL + d0) = o;
        return;
    }
    const float* src; ushort* dst; float scale = 1.0f; int K, N, bx, by;
    if (bid < 5120) {
        int b = bid - 4096; int z = b >> 8; int rem = b & 255;
        bx = rem & 15; by = rem >> 4; K = 512; N = 512;
        src = (z == 0) ? wq : (z == 1) ? wk : (z == 2) ? wv : wo;
        dst = (z < 3) ? wqkvT + (size_t)z * 512 * 512 : woT;
        scale = (z == 0) ? qsc : 1.0f;
    } else if (bid < 5632) {
        int b = bid - 5120; bx = b & 31; by = b >> 5; K = 512; N = 1024; src = w1; dst = w1T;
    } else if (bid < 6144) {
        int b = bid - 5632; bx = b & 15; by = b >> 4; K = 1024; N = 512; src = w2; dst = w2T;
    } else {
        int i = (bid - 6144) * 256 + tid;
        if (i < 512)       bqkv[i] = bq[i] * qsc;
        else if (i < 1024) bqkv[i] = bk[i - 512];
        else if (i < 1536) bqkv[i] = bv[i - 1024];
        return;
    }
    int tx = tid & 31, ty = tid >> 5;
    int n0 = bx * 32, k0 = by * 32;
#pragma unroll
    for (int i = 0; i < 4; ++i)
        tls[ty + i * 8][tx] = f2bf(src[(size_t)(k0 + ty + i * 8) * N + n0 + tx] * scale);
    __syncthreads();
#pragma unroll
    for (int i = 0; i < 4; ++i)
        dst[(size_t)(n0 + ty + i * 8) * K + k0 + tx] = tls[tx][ty + i * 8];
}

// ---------------------------------------------------------------- LDS-staged GEMM
// BMT x BNT tile, 4 waves (2x2), BK=64, dbuf.
// COMBA: A reg-staged as (O0+O1)/(l0+l1) (fused KSPLIT combine + normalize).
// MODE 0: bf16 out (+ReLU opt); 1: f32 out;
// MODE 2: QKV split; V written COLUMN-PERMUTED (tau^-1) so attn can DMA it.
template<int MODE, bool RELU, int BMT, int BNT, bool COMBA>
__global__ __launch_bounds__(256) void k_gemm_lds(
    const ushort* __restrict__ A, const ushort* __restrict__ A2,
    const float* __restrict__ lpb,
    const ushort* __restrict__ BT,
    const float* __restrict__ bias, void* __restrict__ C0,
    void* __restrict__ C1, void* __restrict__ C2,
    int M, int N, int K)
{
    constexpr int MR = BMT / 32;
    constexpr int NR = BNT / 32;
    __shared__ __attribute__((aligned(16))) ushort As[2][BMT * BKG];
    __shared__ __attribute__((aligned(16))) ushort Bs[2][BNT * BKG];

    const int tid = threadIdx.x;
    const int w = tid >> 6, l = tid & 63;
    const int lr = l & 15, lg = l >> 4;
    const int wr = w >> 1, wc = w & 1;

    int bx = blockIdx.x, by = blockIdx.y;
    {   // XCD-aware swizzle (bijective; gridDim.y % 8 == 0 for all our calls)
        int nx = gridDim.x, ny = gridDim.y;
        if ((ny & 7) == 0) {
            int lin = bx + nx * by;
            int xcd = lin & 7, idx = lin >> 3;
            int per = ny >> 3;
            by = xcd * per + (idx % per);
            bx = idx / per;
        }
    }
    const int brow0 = by * BMT;
    const int bcol0 = bx * BNT;
    const int swz = lr & 7;

    f32x4 acc[MR][NR] = {};
    const int nks = K >> 6;

#define STAGE_B(buf, k0)                                                        \
    {                                                                           \
        _Pragma("unroll")                                                       \
        for (int i = 0; i < BNT / 32; ++i) {                                    \
            int gi = w * (BNT * 2) + i * 64 + l;                                \
            int row = gi >> 3, slot = gi & 7;                                   \
            int g = slot ^ (row & 7);                                           \
            __builtin_amdgcn_global_load_lds(                                   \
                (as1_uint*)(BT + (size_t)(bcol0 + row) * K + (k0) + g * 8),     \
                (as3_uint*)(&Bs[buf][gi * 8]), 16, 0, 0);                       \
        }                                                                       \
    }
#define STAGE_A_DMA(buf, k0)                                                    \
    {                                                                           \
        _Pragma("unroll")                                                       \
        for (int i = 0; i < BMT / 32; ++i) {                                    \
            int gi = w * (BMT * 2) + i * 64 + l;                                \
            int row = gi >> 3, slot = gi & 7;                                   \
            int g = slot ^ (row & 7);                                           \
            __builtin_amdgcn_global_load_lds(                                   \
                (as1_uint*)(A + (size_t)(brow0 + row) * K + (k0) + g * 8),      \
                (as3_uint*)(&As[buf][gi * 8]), 16, 0, 0);                       \
        }                                                                       \
    }
#define STAGE_A_COMB(buf, k0)                                                   \
    {                                                                           \
        int head = (k0) >> 6;                                                   \
        _Pragma("unroll")                                                       \
        for (int i = 0; i < BMT / 32; ++i) {                                    \
            int gi = w * (BMT * 2) + i * 64 + l;                                \
            int row = gi >> 3, slot = gi & 7;                                   \
            int g = slot ^ (row & 7);                                           \
            size_t off = (size_t)(brow0 + row) * K + (k0) + g * 8;              \
            bf16x4 a0 = *(const bf16x4*)(A + off);                              \
            bf16x4 a1 = *(const bf16x4*)(A + off + 4);                          \
            bf16x4 c0 = *(const bf16x4*)(A2 + off);                             \
            bf16x4 c1 = *(const bf16x4*)(A2 + off + 4);                         \
            float l0 = lpb[(size_t)head * NROWS + brow0 + row];                 \
            float l1 = lpb[(size_t)(8 + head) * NROWS + brow0 + row];           \
            float r = 1.0f / (l0 + l1);                                         \
            u32x4 pk;                                                           \
            pk[0] = pk_bf16((bf2f(a0[0]) + bf2f(c0[0])) * r,                    \
                            (bf2f(a0[1]) + bf2f(c0[1])) * r);                   \
            pk[1] = pk_bf16((bf2f(a0[2]) + bf2f(c0[2])) * r,                    \
                            (bf2f(a0[3]) + bf2f(c0[3])) * r);                   \
            pk[2] = pk_bf16((bf2f(a1[0]) + bf2f(c1[0])) * r,                    \
                            (bf2f(a1[1]) + bf2f(c1[1])) * r);                   \
            pk[3] = pk_bf16((bf2f(a1[2]) + bf2f(c1[2])) * r,                    \
                            (bf2f(a1[3]) + bf2f(c1[3])) * r);                   \
            *(u32x4*)(&As[buf][gi * 8]) = pk;                                   \
        }                                                                       \
    }
#define STAGE(buf, k0)                                                          \
    {                                                                           \
        if constexpr (COMBA) { STAGE_A_COMB(buf, k0); }                         \
        else                 { STAGE_A_DMA(buf, k0); }                          \
        STAGE_B(buf, k0);                                                       \
    }

    STAGE(0, 0);
    __syncthreads();

    int buf = 0;
    for (int ks = 0; ks < nks; ++ks) {
        if (ks + 1 < nks) STAGE(buf ^ 1, (ks + 1) * BKG);
#pragma unroll
        for (int kk = 0; kk < 2; ++kk) {
            short8 af[MR], bfr[NR];
#pragma unroll
            for (int m = 0; m < MR; ++m) {
                int row = wr * (BMT / 2) + m * 16 + lr;
                int slot = (kk * 4 + lg) ^ swz;
                af[m] = *(const short8*)(&As[buf][row * 64 + slot * 8]);
            }
#pragma unroll
            for (int n = 0; n < NR; ++n) {
                int row = wc * (BNT / 2) + n * 16 + lr;
                int slot = (kk * 4 + lg) ^ swz;
                bfr[n] = *(const short8*)(&Bs[buf][row * 64 + slot * 8]);
            }
#pragma unroll
            for (int m = 0; m < MR; ++m)
#pragma unroll
                for (int n = 0; n < NR; ++n)
                    acc[m][n] = __builtin_amdgcn_mfma_f32_16x16x32_bf16(af[m], bfr[n], acc[m][n], 0, 0, 0);
        }
        __syncthreads();
        buf ^= 1;
    }
#undef STAGE
#undef STAGE_A_COMB
#undef STAGE_A_DMA
#undef STAGE_B

#pragma unroll
    for (int n = 0; n < NR; ++n) {
        int col = bcol0 + wc * (BNT / 2) + n * 16 + lr;
        float bv = bias[col];
#pragma unroll
        for (int m = 0; m < MR; ++m) {
            int row0 = brow0 + wr * (BMT / 2) + m * 16 + 4 * lg;
            if constexpr (MODE == 2) {
                int seg = col >> 9, lc = col & 511;
                if (seg == 2) {
                    bf16x4 pk;
#pragma unroll
                    for (int j = 0; j < 4; ++j) pk[j] = f2bf(acc[m][n][j] + bv);
                    // tau^-1 column permutation: key 4-group kg -> position
                    // 32*k3 + 16*k1 + 8*k0 + 4*k2 within its 64-key tile.
                    int kg  = (row0 >> 2) & 15;
                    int pos = (row0 & ~63) + ((kg & 8) << 2) + ((kg & 2) << 3)
                              + ((kg & 1) << 3) + (kg & 4);
                    *(bf16x4*)((ushort*)C2 + (size_t)lc * M + pos) = pk;
                } else {
                    ushort* dst = (seg == 0) ? (ushort*)C0 : (ushort*)C1;
#pragma unroll
                    for (int j = 0; j < 4; ++j)
                        dst[(size_t)(row0 + j) * 512 + lc] = f2bf(acc[m][n][j] + bv);
                }
            } else if constexpr (MODE == 0) {
#pragma unroll
                for (int j = 0; j < 4; ++j) {
                    float v = acc[m][n][j] + bv;
                    if (RELU) v = fmaxf(v, 0.0f);
                    ((ushort*)C0)[(size_t)(row0 + j) * N + col] = f2bf(v);
                }
            } else {
#pragma unroll
                for (int j = 0; j < 4; ++j)
                    ((float*)C0)[(size_t)(row0 + j) * N + col] = acc[m][n][j] + bv;
            }
        }
    }
}

// ---------------------------------------------------------------- flash attention
// 8 waves x 32 q-rows (2 q-subtiles share K/V register fragments). KSPLIT=2.
// K AND V both staged via global_load_lds (V pre-permuted in QKV epilogue).
// Static-max exp2 softmax; l via ones-MFMA.
__global__ __launch_bounds__(512, 4) void k_attn(
    const ushort* __restrict__ Q, const ushort* __restrict__ Kb,
    const ushort* __restrict__ Vt, const int* __restrict__ tokens,
    ushort* __restrict__ O0, ushort* __restrict__ O1,
    float* __restrict__ lp)
{
    __shared__ __attribute__((aligned(16))) ushort Kl[2][KVB * 64];
    __shared__ __attribute__((aligned(16))) ushort Vl[2][KVB * 64];
    __shared__ __attribute__((aligned(16))) ushort Mbh[KHALF];
    __shared__ int padf[KHALF / KVB];

    const int tid = threadIdx.x;
    const int w = tid >> 6, l = tid & 63;
    const int lr = l & 15, lg = l >> 4;
    const int swz = lr & 7;

    // XCD swizzle: lin bijective over 0..511 (grid 8x8x8)
    int lin = blockIdx.x + 8 * (blockIdx.y + 8 * blockIdx.z);  // 0..511
    int xcd = lin & 7, idx = lin >> 3;           // idx 0..63
    int qt  = idx & 7;
    int grp = xcd + 8 * (idx >> 3);              // 0..63
    int ks  = grp & 1;
    int h   = (grp >> 1) & 7;
    int b   = grp >> 4;

    const int q0  = qt * 256 + w * 32;
    const int kb0 = ks * KHALF;

    // staging geometry: thread -> row srow (0..63), granule sg (0..7),
    // pre-swizzled source granule sgx; both K and V DMA'd linearly.
    const int gi   = w * 64 + l;
    const int srow = gi >> 3;
    const int sg   = gi & 7;
    const int sgx  = sg ^ (srow & 7);
    const ushort* Ksrc = Kb + ((size_t)(b * T_SEQ + kb0) + srow) * D_MODEL + h * D_K + sgx * 8;
    const ushort* Vsrc = Vt + (size_t)(h * D_K + srow) * NROWS + b * T_SEQ + kb0 + sgx * 8;

#define KVSTAGE(bufi, kt_)                                                      \
    {                                                                           \
        __builtin_amdgcn_global_load_lds(                                       \
            (as1_uint*)(Ksrc + (size_t)(kt_) * KVB * D_MODEL),                  \
            (as3_uint*)(&Kl[bufi][gi * 8]), 16, 0, 0);                          \
        __builtin_amdgcn_global_load_lds(                                       \
            (as1_uint*)(Vsrc + (kt_) * KVB),                                    \
            (as3_uint*)(&Vl[bufi][gi * 8]), 16, 0, 0);                          \
    }

    const ushort* Qh = Q + (size_t)b * T_SEQ * D_MODEL + h * D_K;
    short8 aq[2][2];
#pragma unroll
    for (int qs = 0; qs < 2; ++qs)
#pragma unroll
        for (int c2 = 0; c2 < 2; ++c2)
            aq[qs][c2] = *(const short8*)(Qh + (size_t)(q0 + qs * 16 + lr) * D_MODEL
                                          + c2 * 32 + 8 * lg);

    // ones vector (bf16 1.0) for l-sum MFMA
    short8 vones;
#pragma unroll
    for (int i = 0; i < 8; ++i) vones[i] = (short)0x3F80;

    // mask staging (bf16) + per-tile pad bitmap for this key half
    const int* tk = tokens + b * T_SEQ + kb0;
#pragma unroll
    for (int it = 0; it < KHALF / 512; ++it) {
        int i = tid + it * 512;
        bool pad = (tk[i] == 0);
        Mbh[i] = pad ? (ushort)0xFF7F : (ushort)0;
        unsigned long long bal = __ballot(pad);
        if (l == 0) padf[it * 8 + w] = (bal != 0ull);
    }

    f32x4 acc[2][4] = {};
    f32x4 acc_l[2] = {};

    KVSTAGE(0, 0);
    __syncthreads();

    int buf = 0;
    const int NT = KHALF / KVB;   // 16
#pragma unroll 2
    for (int kt = 0; kt < NT; ++kt) {
        if (kt + 1 < NT) KVSTAGE(buf ^ 1, kt + 1);

        const ushort* Kt = Kl[buf];
        const ushort* Vb = Vl[buf];
        bool havePad = padf[kt];

        // ---- QK^T + softmax, kb-pairs; K-frags shared by both q-subtiles
        unsigned dw[2][4][2];   // [qs][kb][half] packed bf16 P pairs
#pragma unroll
        for (int kh = 0; kh < 2; ++kh) {
            short8 kf[2][2];
#pragma unroll
            for (int i = 0; i < 2; ++i)
#pragma unroll
                for (int c2 = 0; c2 < 2; ++c2)
                    kf[i][c2] = *(const short8*)((const char*)Kt
                                + ((2 * kh + i) * 16 + lr) * 128
                                + (((c2 * 4 + lg) ^ swz) * 16));
#pragma unroll
            for (int qs = 0; qs < 2; ++qs)
#pragma unroll
                for (int i = 0; i < 2; ++i) {
                    int kb = 2 * kh + i;
                    __builtin_amdgcn_s_setprio(1);
                    f32x4 sf = {};
                    sf = __builtin_amdgcn_mfma_f32_16x16x32_bf16(kf[i][0], aq[qs][0], sf, 0, 0, 0);
                    sf = __builtin_amdgcn_mfma_f32_16x16x32_bf16(kf[i][1], aq[qs][1], sf, 0, 0, 0);
                    __builtin_amdgcn_s_setprio(0);
                    if (havePad) {
                        bf16x4 m4 = *(const bf16x4*)(Mbh + kt * KVB + kb * 16 + 4 * lg);
#pragma unroll
                        for (int j = 0; j < 4; ++j) sf[j] += bf2f(m4[j]);
                    }
                    dw[qs][kb][0] = pk_bf16(exp2f(sf[0]), exp2f(sf[1]));
                    dw[qs][kb][1] = pk_bf16(exp2f(sf[2]), exp2f(sf[3]));
                }
        }

        // ---- PV, c-pairs; V-frags shared by both q-subtiles; l via ones-MFMA
#pragma unroll
        for (int ch = 0; ch < 2; ++ch) {
            short8 vf[2][2];
#pragma unroll
            for (int i = 0; i < 2; ++i)
#pragma unroll
                for (int kk = 0; kk < 2; ++kk)
                    vf[i][kk] = *(const short8*)((const char*)Vb
                                + ((2 * ch + i) * 16 + lr) * 128
                                + (((kk * 4 + lg) ^ swz) * 16));
            __builtin_amdgcn_s_setprio(1);
#pragma unroll
            for (int qs = 0; qs < 2; ++qs) {
                u32x4 pw0 = { dw[qs][0][0], dw[qs][0][1], dw[qs][1][0], dw[qs][1][1] };
                u32x4 pw1 = { dw[qs][2][0], dw[qs][2][1], dw[qs][3][0], dw[qs][3][1] };
                short8 pa0 = __builtin_bit_cast(short8, pw0);
                short8 pa1 = __builtin_bit_cast(short8, pw1);
#pragma unroll
                for (int i = 0; i < 2; ++i) {
                    int c = 2 * ch + i;
                    acc[qs][c] = __builtin_amdgcn_mfma_f32_16x16x32_bf16(vf[i][0], pa0, acc[qs][c], 0, 0, 0);
                    acc[qs][c] = __builtin_amdgcn_mfma_f32_16x16x32_bf16(vf[i][1], pa1, acc[qs][c], 0, 0, 0);
                }
                if (ch == 0) {
                    acc_l[qs] = __builtin_amdgcn_mfma_f32_16x16x32_bf16(vones, pa0, acc_l[qs], 0, 0, 0);
                    acc_l[qs] = __builtin_amdgcn_mfma_f32_16x16x32_bf16(vones, pa1, acc_l[qs], 0, 0, 0);
                }
            }
            __builtin_amdgcn_s_setprio(0);
        }

        __syncthreads();
        buf ^= 1;
    }
#undef KVSTAGE

    // ---- unnormalized partial output + l (all rows of acc_l equal l[q=lr])
    ushort* Op = (ks == 0) ? O0 : O1;
#pragma unroll
    for (int qs = 0; qs < 2; ++qs) {
        ushort* orow = Op + (size_t)(b * T_SEQ + q0 + qs * 16 + lr) * D_MODEL + h * D_K;
#pragma unroll
        for (int c = 0; c < 4; ++c) {
            bf16x4 pk;
#pragma unroll
            for (int j = 0; j < 4; ++j) pk[j] = f2bf(acc[qs][c][j]);
            *(bf16x4*)(orow + c * 16 + 4 * lg) = pk;
        }
        if (l < 16)
            lp[(size_t)(ks * 8 + h) * NROWS + b * T_SEQ + q0 + qs * 16 + l] = acc_l[qs][0];
    }
}

// ---------------------------------------------------------------- add + layernorm
template<bool A_BF16, bool RES_BF16, bool OUT_F32>
__global__ __launch_bounds__(256) void k_ln(
    const void* __restrict__ A, const void* __restrict__ Res,
    const float* __restrict__ g, const float* __restrict__ bb,
    float* __restrict__ of, ushort* __restrict__ ob)
{
    int row = blockIdx.x * 4 + (threadIdx.x >> 6);
    int l = threadIdx.x & 63;
    float v[8];
    float s = 0.0f, ss = 0.0f;
#pragma unroll
    for (int i = 0; i < 2; ++i) {
        int d0 = i * 256 + l * 4;
        f32x4 va, vb;
        if (A_BF16) {
            bf16x4 t = *(const bf16x4*)((const ushort*)A + (size_t)row * D_MODEL + d0);
#pragma unroll
            for (int j = 0; j < 4; ++j) va[j] = bf2f(t[j]);
        } else {
            va = *(const f32x4*)((const float*)A + (size_t)row * D_MODEL + d0);
        }
        if (RES_BF16) {
            bf16x4 t = *(const bf16x4*)((const ushort*)Res + (size_t)row * D_MODEL + d0);
#pragma unroll
            for (int j = 0; j < 4; ++j) vb[j] = bf2f(t[j]);
        } else {
            vb = *(const f32x4*)((const float*)Res + (size_t)row * D_MODEL + d0);
        }
#pragma unroll
        for (int j = 0; j < 4; ++j) {
            float x = va[j] + vb[j];
            v[i * 4 + j] = x; s += x; ss += x * x;
        }
    }
#pragma unroll
    for (int d = 1; d < 64; d <<= 1) { s += __shfl_xor(s, d); ss += __shfl_xor(ss, d); }
    float mu  = s * (1.0f / 512.0f);
    float var = ss * (1.0f / 512.0f) - mu * mu;
    float rs  = rsqrtf(var + 1e-5f);
#pragma unroll
    for (int i = 0; i < 2; ++i)
#pragma unroll
        for (int j = 0; j < 4; ++j) {
            int d = i * 256 + l * 4 + j;
            float o = (v[i * 4 + j] - mu) * rs * g[d] + bb[d];
            if (OUT_F32) of[(size_t)row * D_MODEL + d] = o;
            else         ob[(size_t)row * D_MODEL + d] = f2bf(o);
        }
}

// ---------------------------------------------------------------- launcher
extern "C" void kernel_launch(void* const* d_in, const int* in_sizes, int n_in,
                              void* d_out, int out_size, void* d_ws, size_t ws_size,
                              hipStream_t stream)
{
    const int*   tokens = (const int*)  d_in[0];
    const float* emb    = (const float*)d_in[1];
    const float* wq     = (const float*)d_in[2];
    const float* bq     = (const float*)d_in[3];
    const float* wk     = (const float*)d_in[4];
    const float* bk     = (const float*)d_in[5];
    const float* wv     = (const float*)d_in[6];
    const float* bv     = (const float*)d_in[7];
    const float* wo     = (const float*)d_in[8];
    const float* bo     = (const float*)d_in[9];
    const float* w1     = (const float*)d_in[10];
    const float* b1     = (const float*)d_in[11];
    const float* w2     = (const float*)d_in[12];
    const float* b2     = (const float*)d_in[13];
    const float* ln1_g  = (const float*)d_in[14];
    const float* ln1_b  = (const float*)d_in[15];
    const float* ln2_g  = (const float*)d_in[16];
    const float* ln2_b  = (const float*)d_in[17];

    char* ws = (char*)d_ws;
    ushort* xb   = (ushort*)(ws + 0);              //  8 MB  x bf16 (LN1 residual)
    ushort* Qb   = (ushort*)(ws + 8388608);        //  8 MB  Q; then WO out
    ushort* Kbuf = (ushort*)(ws + 16777216);       //  8 MB  K \ later ff1 (16 MB)
    ushort* Vt   = (ushort*)(ws + 25165824);       //  8 MB  V^T permuted /
    ushort* atb  = (ushort*)(ws + 33554432);       //  8 MB  O-partial0; then h bf16
    ushort* AVb  = (ushort*)(ws + 41943040);       //  8 MB  O-partial1; then ff2
    ushort* wqkvT = (ushort*)(ws + 50331648);      // 1.5 MB
    ushort* woT  = wqkvT + 1536 * 512;
    ushort* w1T  = woT + 262144;
    ushort* w2T  = w1T + 524288;
    float*  bqkv = (float*)(w2T + 524288);         // 6 KB
    float*  lpart = bqkv + 2048;                   // 512 KB (2*8*NROWS f32)

    ushort* ff1b = Kbuf;
    ushort* ff2b = AVb;

    float* out_f    = (float*)d_out;
    float* mask_out = out_f + (size_t)NROWS * D_MODEL;

    // exp2-domain score scale: 1/sqrt(64) * log2(e)
    const float QSC = 0.18033688011112042f;

    k_prep<<<6150, 256, 0, stream>>>(
        tokens, emb, wq, wk, wv, wo, w1, w2, bq, bk, bv,
        xb, mask_out, wqkvT, woT, w1T, w2T, bqkv, QSC);

    // QKV: 64x128 tiles -> 1536 blocks (V written column-permuted)
    k_gemm_lds<2, false, 64, 128, false><<<dim3(12, 128), 256, 0, stream>>>(
        xb, nullptr, nullptr, wqkvT, bqkv, Qb, Kbuf, Vt, NROWS, 1536, 512);

    k_attn<<<dim3(8, 8, 8), 512, 0, stream>>>(
        Qb, Kbuf, Vt, tokens, atb, AVb, lpart);

    // WO GEMM with fused KSPLIT combine+normalize; 64x64 tiles; out -> Qb.
    k_gemm_lds<0, false, 64, 64, true><<<dim3(8, 128), 256, 0, stream>>>(
        atb, AVb, lpart, woT, bo, Qb, nullptr, nullptr, NROWS, 512, 512);

    // LN1: h = LN(wo_out + x) -> bf16 into atb
    k_ln<true, true, false><<<NROWS / 4, 256, 0, stream>>>(
        Qb, xb, ln1_g, ln1_b, nullptr, atb);

    // FF1: 64x64 tiles -> 2048 blocks
    k_gemm_lds<0, true, 64, 64, false><<<dim3(16, 128), 256, 0, stream>>>(
        atb, nullptr, nullptr, w1T, b1, ff1b, nullptr, nullptr, NROWS, 1024, 512);
    // FF2: 64x64 tiles -> 1024 blocks
    k_gemm_lds<0, false, 64, 64, false><<<dim3(8, 128), 256, 0, stream>>>(
        ff1b, nullptr, nullptr, w2T, b2, ff2b, nullptr, nullptr, NROWS, 512, 1024);

    // LN2: out = LN(ff + h) -> f32 to d_out   (h = atb)
    k_ln<true, true, true><<<NROWS / 4, 256, 0, stream>>>(
        ff2b, atb, ln2_g, ln2_b, out_f, nullptr);
}